// Round 4
// baseline (108.414 us; speedup 1.0000x reference)
//
#include <hip/hip_runtime.h>
#include <hip/hip_bf16.h>

// SubbandCompose R4: rows-per-lane DFT, m-outer / p-inner fully-unrolled.
//
// y[t] = X[0] + (-1)^t X[64] + 2*sum_{m=1..63} X[m] cos(pi*m*t/64), t=0..64.
// With p = min(t,64-t):  E_p = sum_{even m} w_m X[m] cos(pi*m*p/64),
//                        O_p = sum_{odd  m} w_m X[m] cos(pi*m*p/64),
//   y[p] = E_p + O_p,  y[64-p] = E_p - O_p.  (O_32 is exactly 0.)
// out[s,i,j] = (1/512) * sum_{k=0..5} filt[k*64+j] * y[i+5-k][t(k,j)],
//   t(k,j) = j (k even);  (j==0 ? 64 : 64-j) (k odd).
//
// R4 vs R3: coefficient table transposed to tabT[m][p] and the DFT loop
// swapped to m-outer (fully unrolled): 33 independent FMAs per body into
// persistent E/O accumulators -> no dep chains, X[m] consumed one at a time
// (partial vmcnt waits), s_loads hoistable ahead. Ys pair-packed bf16x2.

#define NF 65
#define NT 8192
#define TRUE_LEN 8187
#define FPW 59              // output frames per wave (64 rows incl. 5 halo)
#define WPB 139             // waves per batch element: ceil(8187/59)
#define TABT_STRIDE 36      // floats per table row (33 padded, 16B aligned)
#define YS_STRIDE 66        // bf16 elems per Ys row

typedef const __attribute__((address_space(4))) float cfloat;

__device__ float d_tabT[NF * TABT_STRIDE];

__global__ void build_tab_kernel() {
    int idx = blockIdx.x * 256 + threadIdx.x;
    if (idx >= NF * TABT_STRIDE) return;
    int m = idx / TABT_STRIDE, p = idx % TABT_STRIDE;
    if (p >= 33) { d_tabT[idx] = 0.0f; return; }
    float w = (m == 0 || m == 64) ? 1.0f : 2.0f;
    int a = (m * p) & 127;                       // cos period 128
    d_tabT[idx] = w * cospif((float)a * (1.0f / 64.0f));
}

__global__ __launch_bounds__(256, 3)
void subband_main_kernel(const float* __restrict__ g_in,
                         const float* __restrict__ g_filt,
                         float* __restrict__ g_out)
{
    __shared__ __hip_bfloat162 Ys2[4][64 * 33];   // wave-private, [r][t-pair]

    const int tid  = threadIdx.x;
    const int lane = tid & 63;
    const int wv   = tid >> 6;
    const int wg   = blockIdx.x * 4 + wv;     // global wave id, 0..2223
    const int s     = wg / WPB;
    const int fbase = (wg % WPB) * FPW;
    int h = fbase + lane;
    if (h > NT - 1) h = NT - 1;               // clamped rows feed only discarded frames

    // ---- this lane's spectrum row -> VGPRs (16x16B + 1); consumed in order,
    // so partial vmcnt waits let FMAs start after the first load returns.
    const float* xr = g_in + ((size_t)s * NT + h) * NF;
    float X[NF];
    #pragma unroll
    for (int c = 0; c < 16; ++c) {
        float t4[4];
        __builtin_memcpy(t4, xr + 4 * c, 16);
        X[4 * c + 0] = t4[0]; X[4 * c + 1] = t4[1];
        X[4 * c + 2] = t4[2]; X[4 * c + 3] = t4[3];
    }
    X[64] = xr[64];

    // ---- stage 1: fully-unrolled m-outer DFT, coefficients via scalar pipe
    float E[33], O[33];
    #pragma unroll
    for (int p = 0; p < 33; ++p) { E[p] = 0.0f; O[p] = 0.0f; }

    cfloat* ct = (cfloat*)(unsigned long long)(const float*)d_tabT;
    #pragma unroll
    for (int m = 0; m < NF; ++m) {
        cfloat* c = ct + m * TABT_STRIDE;
        const float xm = X[m];
        float* acc = (m & 1) ? O : E;         // compile-time after unroll
        #pragma unroll
        for (int p = 0; p < 33; ++p) acc[p] += c[p] * xm;
    }

    // ---- finalize: y[t], pair-packed bf16x2 -> 33 ds_write_b32
    __hip_bfloat162* ys2 = &Ys2[wv][0] + lane * 33;
    #pragma unroll
    for (int q = 0; q < 33; ++q) {
        const int t0 = 2 * q, t1 = 2 * q + 1;
        const float y0 = (t0 <= 32) ? (E[t0] + O[t0]) : (E[64 - t0] - O[64 - t0]);
        const float y1 = (t1 <= 64)
                       ? ((t1 <= 32) ? (E[t1] + O[t1]) : (E[64 - t1] - O[64 - t1]))
                       : 0.0f;
        __hip_bfloat162 pk;
        pk.x = __float2bfloat16(y0);
        pk.y = __float2bfloat16(y1);
        ys2[q] = pk;
    }
    // wave-private LDS, DS pipe in-order within the wave: no barrier needed.

    // ---- stage 2: 6-tap polyphase, rolling window, lane = j
    const __hip_bfloat16* ys = (const __hip_bfloat16*)&Ys2[wv][0];
    const int j = lane;
    float fc[6];
    #pragma unroll
    for (int k = 0; k < 6; ++k) fc[k] = g_filt[k * 64 + j] * (1.0f / 512.0f);
    const int te = j;
    const int to = (j == 0) ? 64 : 64 - j;

    float we[6], wo[6];
    #pragma unroll
    for (int r = 0; r < 5; ++r) {
        we[r] = __bfloat162float(ys[r * YS_STRIDE + te]);
        wo[r] = __bfloat162float(ys[r * YS_STRIDE + to]);
    }
    float* dst = g_out + ((size_t)s * TRUE_LEN + fbase) * 64 + j;

    #pragma unroll
    for (int q = 0; q < FPW; ++q) {
        if (fbase + q >= TRUE_LEN) break;
        we[5] = __bfloat162float(ys[(q + 5) * YS_STRIDE + te]);
        wo[5] = __bfloat162float(ys[(q + 5) * YS_STRIDE + to]);
        const float o = fc[0] * we[5] + fc[1] * wo[4] + fc[2] * we[3]
                      + fc[3] * wo[2] + fc[4] * we[1] + fc[5] * wo[0];
        dst[(size_t)q * 64] = o;
        #pragma unroll
        for (int r = 0; r < 5; ++r) { we[r] = we[r + 1]; wo[r] = wo[r + 1]; }
    }
}

extern "C" void kernel_launch(void* const* d_in, const int* in_sizes, int n_in,
                              void* d_out, int out_size, void* d_ws, size_t ws_size,
                              hipStream_t stream) {
    const float* g_in   = (const float*)d_in[0];  // (16,1,8192,65) fp32
    const float* g_filt = (const float*)d_in[1];  // (384,) fp32
    float* g_out = (float*)d_out;                 // (16,1,8187*64) fp32

    build_tab_kernel<<<10, 256, 0, stream>>>();   // 65*36 = 2340 entries
    subband_main_kernel<<<556, 256, 0, stream>>>(g_in, g_filt, g_out);
}

// Round 5
// 105.832 us; speedup vs baseline: 1.0244x; 1.0244x over previous
//
#include <hip/hip_runtime.h>
#include <hip/hip_bf16.h>

// SubbandCompose R5: E/O wave-pair split, coalesced X staging, 1-buffer LDS.
//
// y[t] = X[0] + (-1)^t X[64] + 2*sum_{m=1..63} X[m] cos(pi*m*t/64), t=0..64.
// p = min(t,64-t):  E_p = sum_{even m} w_m X[m] cos(pi*m*p/64)   (wave 0)
//                   O_p = sum_{odd  m} w_m X[m] cos(pi*m*p/64)   (wave 1)
//   y[p] = E_p + O_p,  y[64-p] = E_p - O_p.  (O_32 = 0 naturally.)
// out[s,i,j] = (1/512) * sum_{k=0..5} filt[k*64+j] * y[i+5-k][t(k,j)],
//   t(k,j) = j (k even);  (j==0 ? 64 : 64-j) (k odd).
//
// Block = 128 thr = 2 waves = one 64-row chunk (59 frames). 2224 blocks ->
// ~8.7 blocks/CU (vs R3's 2.17): latency actually hidden. X staged coalesced
// into LDS (fixes stride-260B L1 thrash), read once into 33 regs/lane.
// LDS buffer (17152 B) repurposed: X(fp32,stride67) -> E/O(bf16) -> Ys(bf16).

#define NF 65
#define NT 8192
#define TRUE_LEN 8187
#define FPW 59
#define CPB 139            // chunks per batch element: ceil(8187/59)
#define XSTR 67            // X staging stride (dwords); odd -> 2-way-max banks
#define TSTR 36            // coefficient table row stride (floats)
#define EOSTR 34           // E/O row stride (bf16)
#define YSTR 66            // Ys row stride (bf16) = 33 packed dwords

typedef const __attribute__((address_space(4))) float cfloat;

__device__ float d_tab[2 * 33 * TSTR];   // [parity][p][n], n-th term: m=2n+par

__global__ void build_tab_kernel() {
    int idx = blockIdx.x * 256 + threadIdx.x;
    if (idx >= 2 * 33 * TSTR) return;
    int par = idx / (33 * TSTR);
    int rem = idx - par * 33 * TSTR;
    int p = rem / TSTR, n = rem - p * TSTR;
    int m = 2 * n + par;
    float v = 0.0f;
    if (n < 33 && m <= 64) {
        float w = (m == 0 || m == 64) ? 1.0f : 2.0f;
        int a = (m * p) & 127;                   // cos period 128
        v = w * cospif((float)a * (1.0f / 64.0f));
    }
    d_tab[idx] = v;
}

__global__ __launch_bounds__(128, 4)
void subband_main_kernel(const float* __restrict__ g_in,
                         const float* __restrict__ g_filt,
                         float* __restrict__ g_out)
{
    __shared__ float smem[64 * XSTR];                            // 17152 B
    __hip_bfloat16* Es = (__hip_bfloat16*)smem;                  // 64 x 34
    __hip_bfloat16* Os = (__hip_bfloat16*)((char*)smem + 4352);  // 64 x 34
    __hip_bfloat16* Yb = (__hip_bfloat16*)((char*)smem + 8704);  // 64 x 66

    const int tid  = threadIdx.x;       // 0..127
    const int lane = tid & 63;
    const int wv   = tid >> 6;          // 0: even-m (E), 1: odd-m (O)
    const int cg   = blockIdx.x;
    const int s     = cg / CPB;
    const int fbase = (cg - s * CPB) * FPW;

    // ---- stage X rows fbase..fbase+63, block-coalesced global reads
    const float* src = g_in + (size_t)s * NT * NF;
    for (int i = tid; i < 64 * NF; i += 128) {
        int r = i / NF, c = i - r * NF;
        int h = fbase + r; if (h > NT - 1) h = NT - 1;  // clamped rows feed only discarded frames
        smem[r * XSTR + c] = src[(size_t)h * NF + c];
    }
    // zero the 2 pad dwords per row (O-wave's n=32 reads one; avoid NaN junk)
    { int r = tid >> 1, sl = NF + (tid & 1); smem[r * XSTR + sl] = 0.0f; }
    __syncthreads();

    // ---- X row -> regs: Xr[n] = X[row][2n + wv]
    const int row = lane;
    float Xr[33];
    #pragma unroll
    for (int n = 0; n < 33; ++n) Xr[n] = smem[row * XSTR + 2 * n + wv];
    __syncthreads();   // all X reads done; E/O overlay the X region

    // ---- stage 1: p-loop, coefficients via scalar pipe (wave-uniform)
    const int tab_off = __builtin_amdgcn_readfirstlane(wv * (33 * TSTR));
    cfloat* ct = (cfloat*)(unsigned long long)(const float*)(d_tab + tab_off);
    __hip_bfloat16* eo = (wv == 0) ? Es : Os;
    for (int p = 0; p < 33; ++p) {
        cfloat* cf = ct + p * TSTR;
        float a0 = 0.0f, a1 = 0.0f, a2 = 0.0f, a3 = 0.0f;
        #pragma unroll
        for (int n = 0; n < 32; n += 4) {
            a0 += cf[n]     * Xr[n];
            a1 += cf[n + 1] * Xr[n + 1];
            a2 += cf[n + 2] * Xr[n + 2];
            a3 += cf[n + 3] * Xr[n + 3];
        }
        a0 += cf[32] * Xr[32];              // tabO[p][32]=0 covers m=65
        eo[row * EOSTR + p] = __float2bfloat16((a0 + a2) + (a1 + a3));
    }
    __syncthreads();

    // ---- combine E/O -> y pairs, write Ys (disjoint overlay region)
    {
        const int crow = wv * 32 + (lane & 31);
        const int g = lane >> 5;
        for (int it = 0; it < 17; ++it) {
            const int q = g * 17 + it;
            if (q > 32) break;
            const int t0 = 2 * q, t1 = 2 * q + 1;
            const int p0 = (t0 <= 32) ? t0 : 64 - t0;
            const float e0 = __bfloat162float(Es[crow * EOSTR + p0]);
            const float o0 = __bfloat162float(Os[crow * EOSTR + p0]);
            const float y0 = (t0 <= 32) ? e0 + o0 : e0 - o0;
            float y1 = 0.0f;
            if (t1 <= 64) {
                const int p1 = (t1 <= 32) ? t1 : 64 - t1;
                const float e1 = __bfloat162float(Es[crow * EOSTR + p1]);
                const float o1 = __bfloat162float(Os[crow * EOSTR + p1]);
                y1 = (t1 <= 32) ? e1 + o1 : e1 - o1;
            }
            __hip_bfloat162 pk;
            pk.x = __float2bfloat16(y0);
            pk.y = __float2bfloat16(y1);
            *(__hip_bfloat162*)&Yb[crow * YSTR + t0] = pk;
        }
    }
    __syncthreads();

    // ---- stage 2: 6-tap polyphase, rolling window; frames split 30/29
    const int j = lane;
    float fc[6];
    #pragma unroll
    for (int k = 0; k < 6; ++k) fc[k] = g_filt[k * 64 + j] * (1.0f / 512.0f);
    const int te = j;
    const int to = (j == 0) ? 64 : 64 - j;
    const int qlo = wv * 30;
    const int nq  = 30 - wv;

    float we[6], wo[6];
    #pragma unroll
    for (int r = 0; r < 5; ++r) {
        we[r] = __bfloat162float(Yb[(qlo + r) * YSTR + te]);
        wo[r] = __bfloat162float(Yb[(qlo + r) * YSTR + to]);
    }
    float* dst = g_out + ((size_t)s * TRUE_LEN + fbase + qlo) * 64 + j;

    for (int u = 0; u < nq; ++u) {
        if (fbase + qlo + u >= TRUE_LEN) break;
        we[5] = __bfloat162float(Yb[(qlo + u + 5) * YSTR + te]);
        wo[5] = __bfloat162float(Yb[(qlo + u + 5) * YSTR + to]);
        const float o = fc[0] * we[5] + fc[1] * wo[4] + fc[2] * we[3]
                      + fc[3] * wo[2] + fc[4] * we[1] + fc[5] * wo[0];
        dst[(size_t)u * 64] = o;
        #pragma unroll
        for (int r = 0; r < 5; ++r) { we[r] = we[r + 1]; wo[r] = wo[r + 1]; }
    }
}

extern "C" void kernel_launch(void* const* d_in, const int* in_sizes, int n_in,
                              void* d_out, int out_size, void* d_ws, size_t ws_size,
                              hipStream_t stream) {
    const float* g_in   = (const float*)d_in[0];  // (16,1,8192,65) fp32
    const float* g_filt = (const float*)d_in[1];  // (384,) fp32
    float* g_out = (float*)d_out;                 // (16,1,8187*64) fp32

    build_tab_kernel<<<10, 256, 0, stream>>>();   // 2376 entries
    subband_main_kernel<<<16 * CPB, 128, 0, stream>>>(g_in, g_filt, g_out);
}